// Round 5
// baseline (1036.907 us; speedup 1.0000x reference)
//
#include <hip/hip_runtime.h>
#include <hip/hip_bf16.h>

constexpr int N_NODES = 100000;
constexpr int N_EDGES = 3200000;
constexpr int N_PAIRS = 500000;
constexpr int D       = 256;
constexpr int NCHUNK  = 16;
constexpr int CHUNK_NODES = N_NODES / NCHUNK;   // 6250

using frag_ab = __attribute__((ext_vector_type(8))) short;   // 8 bf16
using frag_cd = __attribute__((ext_vector_type(4))) float;   // 4 f32
typedef unsigned short ushort8 __attribute__((ext_vector_type(8)));

static __device__ __forceinline__ float b2f(unsigned short u) {
  return __uint_as_float(((unsigned)u) << 16);
}
static __device__ __forceinline__ unsigned short f2bf(float f) {
  unsigned u = __float_as_uint(f);
  unsigned r = (u + 0x7fff + ((u >> 16) & 1)) >> 16;   // RNE
  return (unsigned short)r;
}

// ---------------------------------------------------------------------------
__global__ void zero_ints(int* __restrict__ p, int n) {
  int i = blockIdx.x * blockDim.x + threadIdx.x;
  if (i < n) p[i] = 0;
}

__global__ void f32_to_bf16(const float4* __restrict__ in, ushort4* __restrict__ out, int n4) {
  int i = blockIdx.x * blockDim.x + threadIdx.x;
  int stride = gridDim.x * blockDim.x;
  for (; i < n4; i += stride) {
    const float4 v = in[i];
    ushort4 o;
    o.x = f2bf(v.x); o.y = f2bf(v.y); o.z = f2bf(v.z); o.w = f2bf(v.w);
    out[i] = o;
  }
}

// cnt2[dst][chunk(src)]++
__global__ void hist2_kernel(const int* __restrict__ ei, int* __restrict__ cnt2) {
  int i = blockIdx.x * blockDim.x + threadIdx.x;
  if (i < N_EDGES) {
    const int src = ei[i];
    const int dst = ei[N_EDGES + i];
    atomicAdd(&cnt2[dst * NCHUNK + src / CHUNK_NODES], 1);
  }
}

// counts[node] = sum_c cnt2[node][c]
__global__ void rowsum_kernel(const int* __restrict__ cnt2, int* __restrict__ counts) {
  const int node = blockIdx.x * blockDim.x + threadIdx.x;
  if (node >= N_NODES) return;
  const int4* r = reinterpret_cast<const int4*>(cnt2 + node * NCHUNK);
  int s = 0;
#pragma unroll
  for (int j = 0; j < NCHUNK / 4; ++j) {
    const int4 v = r[j];
    s += v.x + v.y + v.z + v.w;
  }
  counts[node] = s;
}

// pos2[node][c] = cursor[node] + exclusive_prefix_c(cnt2[node][*])
__global__ void chunkpos_kernel(const int* __restrict__ cnt2, const int* __restrict__ cursor,
                                int* __restrict__ pos2) {
  const int node = blockIdx.x * blockDim.x + threadIdx.x;
  if (node >= N_NODES) return;
  int run = cursor[node];
#pragma unroll
  for (int c = 0; c < NCHUNK; ++c) {
    const int v = cnt2[node * NCHUNK + c];
    pos2[node * NCHUNK + c] = run;
    run += v;
  }
}

// exclusive prefix sum of counts -> cursor (single block, 1024 threads)
__global__ __launch_bounds__(1024) void scan_kernel(const int* __restrict__ counts,
                                                    int* __restrict__ cursor, int n) {
  __shared__ int wsum[16];
  __shared__ int carry;
  const int t = threadIdx.x, lane = t & 63, w = t >> 6;
  if (t == 0) carry = 0;
  __syncthreads();
  for (int base = 0; base < n; base += 1024) {
    int v = (base + t < n) ? counts[base + t] : 0;
    int s = v;
#pragma unroll
    for (int off = 1; off < 64; off <<= 1) {
      int u = __shfl_up(s, off, 64);
      if (lane >= off) s += u;
    }
    if (lane == 63) wsum[w] = s;
    __syncthreads();
    if (t < 16) {
      int ws = wsum[t];
#pragma unroll
      for (int off = 1; off < 16; off <<= 1) {
        int u = __shfl_up(ws, off, 64);
        if (lane >= off) ws += u;
      }
      wsum[t] = ws;
    }
    __syncthreads();
    const int wpre = (w == 0) ? 0 : wsum[w - 1];
    if (base + t < n) cursor[base + t] = carry + wpre + s - v;  // exclusive
    __syncthreads();
    if (t == 0) carry += wsum[15];
    __syncthreads();
  }
}

// XCD-partitioned fill, src-chunk-ordered within each node's list.
constexpr int FILL_SEG = 4096;
__global__ __launch_bounds__(256) void fill2_kernel(const int* __restrict__ ei,
                                                    int* __restrict__ pos2,
                                                    int* __restrict__ csr) {
  const int range = blockIdx.x & 7;
  const int seg   = blockIdx.x >> 3;
  const int base  = seg * FILL_SEG;
  const int lo = range * 12500, hi = lo + 12500;
#pragma unroll
  for (int j = 0; j < FILL_SEG / 256; ++j) {
    const int i = base + j * 256 + threadIdx.x;
    if (i < N_EDGES) {
      const int dst = ei[N_EDGES + i];
      if (dst >= lo && dst < hi) {
        const int src = ei[i];
        const int pos = atomicAdd(&pos2[dst * NCHUNK + src / CHUNK_NODES], 1);
        csr[pos] = src;
      }
    }
  }
}

// out[node] = x[node] + sum_{s in csr[beg:end)} x[s]; bf16 rows, f32 accumulate.
// One wave per node; half-wave covers alternating edges; lane reads 16 B.
// Neighbor lists are src-chunk-ordered -> reads sweep 3.2 MB regions.
__global__ __launch_bounds__(256) void gather_agg_bf16(const ushort* __restrict__ x,
                                                       const int* __restrict__ csr,
                                                       const int* __restrict__ cursor,
                                                       const int* __restrict__ counts,
                                                       ushort* __restrict__ out) {
  const int node = blockIdx.x * 4 + (threadIdx.x >> 6);
  const int lane = threadIdx.x & 63;
  const int half = lane >> 5;
  const int fl   = lane & 31;
  if (node >= N_NODES) return;
  const int beg = cursor[node];
  const int end = beg + counts[node];
  const size_t fo = (size_t)fl * 8;

  float acc[8];
#pragma unroll
  for (int j = 0; j < 8; ++j) acc[j] = 0.f;

  if (half == 0) {
    const ushort8 self = *reinterpret_cast<const ushort8*>(x + (size_t)node * D + fo);
#pragma unroll
    for (int j = 0; j < 8; ++j) acc[j] += b2f(self[j]);
  }

  int o = beg + half;
  for (; o + 6 < end; o += 8) {
    const int s0 = csr[o], s1 = csr[o + 2], s2 = csr[o + 4], s3 = csr[o + 6];
    const ushort8 v0 = *reinterpret_cast<const ushort8*>(x + (size_t)s0 * D + fo);
    const ushort8 v1 = *reinterpret_cast<const ushort8*>(x + (size_t)s1 * D + fo);
    const ushort8 v2 = *reinterpret_cast<const ushort8*>(x + (size_t)s2 * D + fo);
    const ushort8 v3 = *reinterpret_cast<const ushort8*>(x + (size_t)s3 * D + fo);
#pragma unroll
    for (int j = 0; j < 8; ++j)
      acc[j] += (b2f(v0[j]) + b2f(v1[j])) + (b2f(v2[j]) + b2f(v3[j]));
  }
  for (; o < end; o += 2) {
    const ushort8 v = *reinterpret_cast<const ushort8*>(x + (size_t)csr[o] * D + fo);
#pragma unroll
    for (int j = 0; j < 8; ++j) acc[j] += b2f(v[j]);
  }

#pragma unroll
  for (int j = 0; j < 8; ++j) acc[j] += __shfl_xor(acc[j], 32, 64);

  if (half == 0) {
    ushort8 ov;
#pragma unroll
    for (int j = 0; j < 8; ++j) ov[j] = f2bf(acc[j]);
    *reinterpret_cast<ushort8*>(out + (size_t)node * D + fo) = ov;
  }
}

// ---------------------------------------------------------------------------
// C[r][c] = relu( sum_k A[r][k]*W[c][k] + bias[c] ), bf16 in / bf16 out.
// 4 waves, 64x64 tile, K=256 staged in LDS with XOR swizzle.
// ---------------------------------------------------------------------------
__global__ __launch_bounds__(256) void gemm_mfma_bf16(const ushort* __restrict__ A,
                                                      const ushort* __restrict__ W,
                                                      const float* __restrict__ bias,
                                                      ushort* __restrict__ C,
                                                      int M) {
  __shared__ __align__(16) ushort As[64 * 256];
  __shared__ __align__(16) ushort Ws[64 * 256];

  const int t = threadIdx.x;
  const int w = t >> 6, l = t & 63;
  const int row0 = blockIdx.x * 64;
  const int col0 = blockIdx.y * 64;

  {
    const float4 zero4 = {0.f, 0.f, 0.f, 0.f};
#pragma unroll
    for (int i = 0; i < 8; ++i) {
      const int chunk = t + i * 256;
      const int r  = chunk >> 5;
      const int kb = (chunk & 31) << 4;
      const int swz = kb ^ ((r & 7) << 4);
      const int grow = row0 + r;
      float4 av = zero4;
      if (grow < M)
        av = *reinterpret_cast<const float4*>(
            reinterpret_cast<const char*>(A) + (size_t)grow * 512 + kb);
      *reinterpret_cast<float4*>(reinterpret_cast<char*>(As) + r * 512 + swz) = av;
      const float4 wv = *reinterpret_cast<const float4*>(
          reinterpret_cast<const char*>(W) + (size_t)(col0 + r) * 512 + kb);
      *reinterpret_cast<float4*>(reinterpret_cast<char*>(Ws) + r * 512 + swz) = wv;
    }
  }
  __syncthreads();

  const int g  = l >> 4;
  const int fr = l & 15;

  frag_cd acc[4];
#pragma unroll
  for (int c = 0; c < 4; ++c) {
    acc[c][0] = 0.f; acc[c][1] = 0.f; acc[c][2] = 0.f; acc[c][3] = 0.f;
  }

  const int arow = w * 16 + fr;
  const char* Asb = reinterpret_cast<const char*>(As);
  const char* Wsb = reinterpret_cast<const char*>(Ws);
#pragma unroll
  for (int ks = 0; ks < 8; ++ks) {
    const int kb = ks * 64 + g * 16;
    const frag_ab af = *reinterpret_cast<const frag_ab*>(
        Asb + arow * 512 + (kb ^ ((arow & 7) << 4)));
#pragma unroll
    for (int c = 0; c < 4; ++c) {
      const int wrow = c * 16 + fr;
      const frag_ab bf = *reinterpret_cast<const frag_ab*>(
          Wsb + wrow * 512 + (kb ^ ((wrow & 7) << 4)));
      acc[c] = __builtin_amdgcn_mfma_f32_16x16x32_bf16(af, bf, acc[c], 0, 0, 0);
    }
  }
  __syncthreads();

  ushort* Ct = As;
#pragma unroll
  for (int c = 0; c < 4; ++c) {
    const int col = c * 16 + fr;
    const float bv = bias[col0 + col];
#pragma unroll
    for (int r = 0; r < 4; ++r) {
      const int rl = w * 16 + g * 4 + r;
      Ct[rl * 64 + col] = f2bf(fmaxf(acc[c][r] + bv, 0.f));
    }
  }
  __syncthreads();
#pragma unroll
  for (int i = 0; i < 2; ++i) {
    const int chunk = t + i * 256;
    const int r  = chunk >> 3;
    const int cb = (chunk & 7) << 4;
    const int grow = row0 + r;
    if (grow < M)
      *reinterpret_cast<float4*>(reinterpret_cast<char*>(C) + (size_t)grow * 512 + col0 * 2 + cb) =
          *reinterpret_cast<const float4*>(reinterpret_cast<const char*>(Ct) + r * 128 + cb);
  }
}

// ---------------------------------------------------------------------------
// Pair head: one wave per 2 pairs; half-wave reads one h row each.
// ---------------------------------------------------------------------------
__global__ __launch_bounds__(256) void pair_head_bf16(const ushort* __restrict__ h,
                                                      const int* __restrict__ idx,
                                                      const float* __restrict__ W3,
                                                      const float* __restrict__ b3,
                                                      float* __restrict__ out) {
  const int wave = (int)((blockIdx.x * (size_t)blockDim.x + threadIdx.x) >> 6);
  const int lane = threadIdx.x & 63;
  const int half = lane >> 5;
  const int fl   = lane & 31;
  const int p0 = 2 * wave, p1 = 2 * wave + 1;
  if (p0 >= N_PAIRS) return;

  const int ia = idx[2 * p0 + half];
  const int ib = idx[2 * p1 + half];
  const ushort8 va = *reinterpret_cast<const ushort8*>(h + (size_t)ia * D + fl * 8);
  const ushort8 vb = *reinterpret_cast<const ushort8*>(h + (size_t)ib * D + fl * 8);

  const float4 w0a = *reinterpret_cast<const float4*>(W3 + lane * 8);
  const float4 w0b = *reinterpret_cast<const float4*>(W3 + lane * 8 + 4);
  const float4 w1a = *reinterpret_cast<const float4*>(W3 + 512 + lane * 8);
  const float4 w1b = *reinterpret_cast<const float4*>(W3 + 512 + lane * 8 + 4);
  const float w0[8] = {w0a.x, w0a.y, w0a.z, w0a.w, w0b.x, w0b.y, w0b.z, w0b.w};
  const float w1[8] = {w1a.x, w1a.y, w1a.z, w1a.w, w1b.x, w1b.y, w1b.z, w1b.w};

  float l00 = 0.f, l01 = 0.f, l10 = 0.f, l11 = 0.f;
#pragma unroll
  for (int j = 0; j < 8; ++j) {
    const float fa = b2f(va[j]), fb = b2f(vb[j]);
    l00 += fa * w0[j]; l01 += fa * w1[j];
    l10 += fb * w0[j]; l11 += fb * w1[j];
  }
#pragma unroll
  for (int off = 32; off > 0; off >>= 1) {
    l00 += __shfl_down(l00, off, 64);
    l01 += __shfl_down(l01, off, 64);
    l10 += __shfl_down(l10, off, 64);
    l11 += __shfl_down(l11, off, 64);
  }
  if (lane == 0) {
    const float bb0 = b3[0], bb1 = b3[1];
    l00 += bb0; l01 += bb1; l10 += bb0; l11 += bb1;
    const float m0 = fmaxf(l00, l01);
    const float lse0 = m0 + logf(expf(l00 - m0) + expf(l01 - m0));
    const float m1 = fmaxf(l10, l11);
    const float lse1 = m1 + logf(expf(l10 - m1) + expf(l11 - m1));
    float4 o;
    o.x = l00 - lse0; o.y = l01 - lse0; o.z = l10 - lse1; o.w = l11 - lse1;
    *reinterpret_cast<float4*>(out + 4 * (size_t)wave) = o;
  }
}

// ---------------------------------------------------------------------------
extern "C" void kernel_launch(void* const* d_in, const int* in_sizes, int n_in,
                              void* d_out, int out_size, void* d_ws, size_t ws_size,
                              hipStream_t stream) {
  const float* x   = (const float*)d_in[0];
  const int*   ei  = (const int*)d_in[1];
  const int*   idx = (const int*)d_in[2];
  const float* W1  = (const float*)d_in[3];
  const float* b1  = (const float*)d_in[4];
  const float* W2  = (const float*)d_in[5];
  const float* b2  = (const float*)d_in[6];
  const float* W3  = (const float*)d_in[7];
  const float* b3  = (const float*)d_in[8];
  float* out = (float*)d_out;

  const size_t feat = (size_t)N_NODES * D;
  char* ws = (char*)d_ws;
  ushort* xb    = (ushort*)(ws);                 // 51.2 MB
  ushort* aggb  = (ushort*)(ws + 51200000);      // 51.2 MB
  ushort* hb    = (ushort*)(ws + 102400000);     // 51.2 MB
  // cnt2/pos2 alias the hb region: used only during CSR build, before gemm1
  // writes hb. 100k*16 ints each = 6.4 MB.
  int* cnt2     = (int*)(ws + 102400000);
  int* pos2     = (int*)(ws + 102400000 + 6400000);
  ushort* W1b   = (ushort*)(ws + 153600000);
  ushort* W2b   = (ushort*)(ws + 153731072);
  int* counts   = (int*)(ws + 153862144);
  int* cursor   = (int*)(ws + 154262144);
  int* csr      = (int*)(ws + 154662144);

  const dim3 blk(256);
  const dim3 cnt2Grid((N_NODES * NCHUNK + 255) / 256);
  const dim3 nodeThreadGrid((N_NODES + 255) / 256);
  const dim3 edgeGrid((N_EDGES + 255) / 256);
  const int  nseg = (N_EDGES + FILL_SEG - 1) / FILL_SEG;
  const dim3 fillGrid(8 * nseg);
  const dim3 nodeGrid((N_NODES + 3) / 4);
  const dim3 gemmGrid((N_NODES + 63) / 64, D / 64);
  const dim3 pairGrid(((size_t)(N_PAIRS / 2) * 64 + 255) / 256);

  f32_to_bf16<<<dim3(4096), blk, 0, stream>>>((const float4*)x, (ushort4*)xb, (int)(feat / 4));
  f32_to_bf16<<<dim3(64), blk, 0, stream>>>((const float4*)W1, (ushort4*)W1b, 65536 / 4);
  f32_to_bf16<<<dim3(64), blk, 0, stream>>>((const float4*)W2, (ushort4*)W2b, 65536 / 4);

  // ---- chunk-ordered CSR build ----
  zero_ints<<<cnt2Grid, blk, 0, stream>>>(cnt2, N_NODES * NCHUNK);
  hist2_kernel<<<edgeGrid, blk, 0, stream>>>(ei, cnt2);
  rowsum_kernel<<<nodeThreadGrid, blk, 0, stream>>>(cnt2, counts);
  scan_kernel<<<1, 1024, 0, stream>>>(counts, cursor, N_NODES);
  chunkpos_kernel<<<nodeThreadGrid, blk, 0, stream>>>(cnt2, cursor, pos2);
  fill2_kernel<<<fillGrid, blk, 0, stream>>>(ei, pos2, csr);

  // ---- layer 1 ----
  gather_agg_bf16<<<nodeGrid, blk, 0, stream>>>(xb, csr, cursor, counts, aggb);
  gemm_mfma_bf16<<<gemmGrid, blk, 0, stream>>>(aggb, W1b, b1, hb, N_NODES);

  // ---- layer 2 ----
  gather_agg_bf16<<<nodeGrid, blk, 0, stream>>>(hb, csr, cursor, counts, aggb);
  gemm_mfma_bf16<<<gemmGrid, blk, 0, stream>>>(aggb, W2b, b2, hb, N_NODES);

  // ---- pair head ----
  pair_head_bf16<<<pairGrid, blk, 0, stream>>>(hb, idx, W3, b3, out);
}